// Round 3
// baseline (850.446 us; speedup 1.0000x reference)
//
#include <hip/hip_runtime.h>
#include <hip/hip_bf16.h>
#include <math.h>

#define NTOK 2048
#define DM   1024
#define NH   16
#define DH   64

typedef short bf16x8 __attribute__((ext_vector_type(8)));
typedef float f32x4  __attribute__((ext_vector_type(4)));

static __device__ __forceinline__ unsigned short f2bf(float x) {
    union { float f; unsigned u; } v; v.f = x;
    unsigned r = v.u + 0x7fff + ((v.u >> 16) & 1);   // round-to-nearest-even
    return (unsigned short)(r >> 16);
}

// ---------------- proj: out[h,n,k] = sum_d X[n,d] * W[h,d,k] ----------------
// 64x64 output tile (n x k), K-dim = DM chunked by 64, 4x4 micro-tile.
// which==0 (Q): writes bf16 Qbf.  which==1 (K): writes f32 Kw.  which==2 (V): f32 Vw.
__global__ __launch_bounds__(256) void proj_kernel(
    const float* __restrict__ Q, const float* __restrict__ K, const float* __restrict__ V,
    const float* __restrict__ Wq, const float* __restrict__ Wk, const float* __restrict__ Wv,
    unsigned short* __restrict__ Qbf, float* __restrict__ Kw, float* __restrict__ Vw)
{
    __shared__ float Xs[64][65];   // [n][d] pad 65 -> scalar reads 2-way (free)
    __shared__ float Ws[64][64];   // [d][k] unpadded -> contiguous staging
    const int which = blockIdx.z;
    const float* X = which == 0 ? Q : (which == 1 ? K : V);
    const float* W = which == 0 ? Wq : (which == 1 ? Wk : Wv);
    const int h  = blockIdx.y;
    const int n0 = blockIdx.x * 64;
    const int tx = threadIdx.x & 15;   // k group (4 cols)
    const int ty = threadIdx.x >> 4;   // n group (4 rows)
    const float* Wh = W + (size_t)h * DM * DH;

    float acc[4][4];
    #pragma unroll
    for (int i = 0; i < 4; ++i)
        #pragma unroll
        for (int j = 0; j < 4; ++j) acc[i][j] = 0.f;

    for (int d0 = 0; d0 < DM; d0 += 64) {
        #pragma unroll
        for (int t = 0; t < 16; ++t) {
            int idx = threadIdx.x + t * 256;          // 0..4095
            int r = idx >> 6, c = idx & 63;
            Xs[r][c] = X[(size_t)(n0 + r) * DM + d0 + c];
            ((float*)Ws)[idx] = Wh[(size_t)d0 * DH + idx];  // W[h][d0+r][c], contiguous
        }
        __syncthreads();
        #pragma unroll
        for (int dd = 0; dd < 64; ++dd) {
            float a[4], b[4];
            #pragma unroll
            for (int i = 0; i < 4; ++i) a[i] = Xs[ty * 4 + i][dd];
            #pragma unroll
            for (int j = 0; j < 4; ++j) b[j] = Ws[dd][tx * 4 + j];
            #pragma unroll
            for (int i = 0; i < 4; ++i)
                #pragma unroll
                for (int j = 0; j < 4; ++j) acc[i][j] += a[i] * b[j];
        }
        __syncthreads();
    }
    if (which == 0) {
        #pragma unroll
        for (int i = 0; i < 4; ++i) {
            ushort4 u;
            u.x = f2bf(acc[i][0]); u.y = f2bf(acc[i][1]);
            u.z = f2bf(acc[i][2]); u.w = f2bf(acc[i][3]);
            *(ushort4*)&Qbf[((size_t)h * NTOK + n0 + ty * 4 + i) * DH + tx * 4] = u;
        }
    } else {
        float* out = which == 1 ? Kw : Vw;
        #pragma unroll
        for (int i = 0; i < 4; ++i) {
            float4 v = make_float4(acc[i][0], acc[i][1], acc[i][2], acc[i][3]);
            *(float4*)&out[((size_t)h * NTOK + n0 + ty * 4 + i) * DH + tx * 4] = v;
        }
    }
}

// ---------------- knorm: L2-normalize rows of Kw -> bf16 Knbf (one wave per row) ----------------
__global__ __launch_bounds__(256) void knorm_kernel(
    const float* __restrict__ Kw, unsigned short* __restrict__ Knbf)
{
    const int row = blockIdx.x * 4 + (threadIdx.x >> 6);  // [0, NH*NTOK)
    const int k = threadIdx.x & 63;
    float v = Kw[(size_t)row * DH + k];
    float ss = v * v;
    #pragma unroll
    for (int off = 32; off > 0; off >>= 1) ss += __shfl_xor(ss, off, 64);
    v /= fmaxf(sqrtf(ss), 1e-12f);
    Knbf[(size_t)row * DH + k] = f2bf(v);
}

// ---------------- logits (bf16 MFMA): out[h,n,m] = Qw[h,n,:] . Kn[h,m,:] ----------------
// Block 256 = 4 waves; block tile 64(n) x 64(m); wave handles 16(n) x 64(m).
// mfma_f32_16x16x32_bf16: A row = lane&15, k-chunk = (lane>>4)*8; B col = lane&15 (K row,
// since B = Kn^T); C/D: col = lane&15, row = (lane>>4)*4 + reg  [HW-verified m89/m91].
__global__ __launch_bounds__(256) void logits_mfma_kernel(
    const unsigned short* __restrict__ Qbf, const unsigned short* __restrict__ Knbf,
    float* __restrict__ out)
{
    const int h    = blockIdx.z;
    const int n0   = blockIdx.y * 64;
    const int m0   = blockIdx.x * 64;
    const int wave = threadIdx.x >> 6;
    const int lane = threadIdx.x & 63;
    const int lrow = lane & 15;        // A-row / B-col / C-col
    const int kg   = lane >> 4;        // k-chunk (8 elems) / C-row-group

    const unsigned short* Qh = Qbf  + (size_t)h * NTOK * DH;
    const unsigned short* Kh = Knbf + (size_t)h * NTOK * DH;

    const unsigned short* qrow = Qh + (size_t)(n0 + wave * 16 + lrow) * DH + kg * 8;
    const bf16x8 a0 = *(const bf16x8*)(qrow);
    const bf16x8 a1 = *(const bf16x8*)(qrow + 32);

    float* Oh = out + (size_t)h * NTOK * NTOK;
    #pragma unroll
    for (int mt = 0; mt < 4; ++mt) {
        const unsigned short* krow = Kh + (size_t)(m0 + mt * 16 + lrow) * DH + kg * 8;
        const bf16x8 b0 = *(const bf16x8*)(krow);
        const bf16x8 b1 = *(const bf16x8*)(krow + 32);
        f32x4 acc = {0.f, 0.f, 0.f, 0.f};
        acc = __builtin_amdgcn_mfma_f32_16x16x32_bf16(a0, b0, acc, 0, 0, 0);
        acc = __builtin_amdgcn_mfma_f32_16x16x32_bf16(a1, b1, acc, 0, 0, 0);
        #pragma unroll
        for (int i = 0; i < 4; ++i) {
            Oh[(size_t)(n0 + wave * 16 + kg * 4 + i) * NTOK + (m0 + mt * 16 + lrow)] = acc[i];
        }
    }
}

// ---------------- attn: flash-style softmax(logits) @ Vw -> A1[h,n,k] ----------------
// 64 n-rows per block; thread owns 2 rows x 8 k; online max/sum over m-chunks of 64.
__global__ __launch_bounds__(256) void attn_kernel(
    const float* __restrict__ logits, const float* __restrict__ Vw, float* __restrict__ A1)
{
    __shared__ float Ss[64][65];   // logits chunk, then P
    __shared__ float Vs[64][64];   // V chunk [m][k]
    const int h  = blockIdx.y;
    const int n0 = blockIdx.x * 64;
    const int kg = threadIdx.x & 7;
    const int k0 = kg * 8;
    const int rp = threadIdx.x >> 3;       // 0..31
    const int r0 = rp, r1 = rp + 32;
    const float* Lh = logits + (size_t)h * NTOK * NTOK;
    const float* Vh = Vw + (size_t)h * NTOK * DH;
    float acc0[8], acc1[8];
    #pragma unroll
    for (int i = 0; i < 8; ++i) { acc0[i] = 0.f; acc1[i] = 0.f; }
    float m0 = -1e30f, m1 = -1e30f, l0 = 0.f, l1 = 0.f;

    for (int mc = 0; mc < NTOK; mc += 64) {
        #pragma unroll
        for (int t = 0; t < 16; ++t) {
            int idx = threadIdx.x + t * 256;
            int r = idx >> 6, c = idx & 63;
            Ss[r][c] = Lh[(size_t)(n0 + r) * NTOK + mc + c];
            Vs[r][c] = Vh[(size_t)(mc + r) * DH + c];
        }
        __syncthreads();
        float cm0 = -1e30f, cm1 = -1e30f;
        #pragma unroll
        for (int c = 0; c < 8; ++c) {
            cm0 = fmaxf(cm0, Ss[r0][k0 + c]);
            cm1 = fmaxf(cm1, Ss[r1][k0 + c]);
        }
        #pragma unroll
        for (int off = 1; off < 8; off <<= 1) {
            cm0 = fmaxf(cm0, __shfl_xor(cm0, off, 64));
            cm1 = fmaxf(cm1, __shfl_xor(cm1, off, 64));
        }
        const float nm0 = fmaxf(m0, cm0), nm1 = fmaxf(m1, cm1);
        const float sc0 = __expf(m0 - nm0), sc1 = __expf(m1 - nm1);
        float ps0 = 0.f, ps1 = 0.f;
        #pragma unroll
        for (int c = 0; c < 8; ++c) {
            float p0 = __expf(Ss[r0][k0 + c] - nm0); Ss[r0][k0 + c] = p0; ps0 += p0;
            float p1 = __expf(Ss[r1][k0 + c] - nm1); Ss[r1][k0 + c] = p1; ps1 += p1;
        }
        #pragma unroll
        for (int off = 1; off < 8; off <<= 1) {
            ps0 += __shfl_xor(ps0, off, 64);
            ps1 += __shfl_xor(ps1, off, 64);
        }
        l0 = l0 * sc0 + ps0; l1 = l1 * sc1 + ps1;
        m0 = nm0; m1 = nm1;
        #pragma unroll
        for (int i = 0; i < 8; ++i) { acc0[i] *= sc0; acc1[i] *= sc1; }
        __syncthreads();   // all P written before GEMM reads
        #pragma unroll
        for (int mm = 0; mm < 64; ++mm) {
            const float p0 = Ss[r0][mm], p1 = Ss[r1][mm];
            const float4 va = *(const float4*)&Vs[mm][k0];
            const float4 vb = *(const float4*)&Vs[mm][k0 + 4];
            acc0[0] += p0 * va.x; acc0[1] += p0 * va.y; acc0[2] += p0 * va.z; acc0[3] += p0 * va.w;
            acc0[4] += p0 * vb.x; acc0[5] += p0 * vb.y; acc0[6] += p0 * vb.z; acc0[7] += p0 * vb.w;
            acc1[0] += p1 * va.x; acc1[1] += p1 * va.y; acc1[2] += p1 * va.z; acc1[3] += p1 * va.w;
            acc1[4] += p1 * vb.x; acc1[5] += p1 * vb.y; acc1[6] += p1 * vb.z; acc1[7] += p1 * vb.w;
        }
        __syncthreads();   // before restaging Ss/Vs
    }
    const float inv0 = 1.f / l0, inv1 = 1.f / l1;
    float* O0 = &A1[((size_t)h * NTOK + n0 + r0) * DH + k0];
    float* O1 = &A1[((size_t)h * NTOK + n0 + r1) * DH + k0];
    *(float4*)&O0[0] = make_float4(acc0[0] * inv0, acc0[1] * inv0, acc0[2] * inv0, acc0[3] * inv0);
    *(float4*)&O0[4] = make_float4(acc0[4] * inv0, acc0[5] * inv0, acc0[6] * inv0, acc0[7] * inv0);
    *(float4*)&O1[0] = make_float4(acc1[0] * inv1, acc1[1] * inv1, acc1[2] * inv1, acc1[3] * inv1);
    *(float4*)&O1[4] = make_float4(acc1[4] * inv1, acc1[5] * inv1, acc1[6] * inv1, acc1[7] * inv1);
}

// ---------------- outlin: out[n,j] = sum_c A1row[n,c]*W0[j,c] + b0[j] ----------------
__global__ __launch_bounds__(256) void outlin_kernel(
    const float* __restrict__ A1, const float* __restrict__ W0,
    const float* __restrict__ b0, float* __restrict__ out)
{
    __shared__ float As[64][65];
    __shared__ float Ws[64][65];
    const int j0 = blockIdx.x * 64;
    const int n0 = blockIdx.y * 64;
    const int tx = threadIdx.x & 15;   // j group
    const int ty = threadIdx.x >> 4;   // n group
    float acc[4][4];
    #pragma unroll
    for (int i = 0; i < 4; ++i)
        #pragma unroll
        for (int j = 0; j < 4; ++j) acc[i][j] = 0.f;

    for (int c0 = 0; c0 < NH * DH; c0 += 64) {
        const int h = c0 >> 6;   // chunk == one head slab; A1row[n, c0+c] = A1[h][n][c]
        #pragma unroll
        for (int t = 0; t < 16; ++t) {
            int idx = threadIdx.x + t * 256;
            int r = idx >> 6, c = idx & 63;
            As[r][c] = A1[((size_t)h * NTOK + n0 + r) * DH + c];
            Ws[r][c] = W0[(size_t)(j0 + r) * (NH * DH) + c0 + c];
        }
        __syncthreads();
        #pragma unroll
        for (int cc = 0; cc < 64; ++cc) {
            float a[4], b[4];
            #pragma unroll
            for (int i = 0; i < 4; ++i) a[i] = As[ty * 4 + i][cc];
            #pragma unroll
            for (int j = 0; j < 4; ++j) b[j] = Ws[tx * 4 + j][cc];
            #pragma unroll
            for (int i = 0; i < 4; ++i)
                #pragma unroll
                for (int j = 0; j < 4; ++j) acc[i][j] += a[i] * b[j];
        }
        __syncthreads();
    }
    #pragma unroll
    for (int i = 0; i < 4; ++i) {
        const int n = n0 + ty * 4 + i;
        float4 v = make_float4(acc[i][0] + b0[j0 + tx * 4 + 0],
                               acc[i][1] + b0[j0 + tx * 4 + 1],
                               acc[i][2] + b0[j0 + tx * 4 + 2],
                               acc[i][3] + b0[j0 + tx * 4 + 3]);
        *(float4*)&out[(size_t)n * (NH * DH) + j0 + tx * 4] = v;
    }
}

extern "C" void kernel_launch(void* const* d_in, const int* in_sizes, int n_in,
                              void* d_out, int out_size, void* d_ws, size_t ws_size,
                              hipStream_t stream)
{
    const float* Q  = (const float*)d_in[0];
    const float* K  = (const float*)d_in[1];
    const float* V  = (const float*)d_in[2];
    const float* Wq = (const float*)d_in[3];
    const float* Wk = (const float*)d_in[4];
    const float* Wv = (const float*)d_in[5];
    const float* W0 = (const float*)d_in[6];
    const float* b0 = (const float*)d_in[7];

    float* logits = (float*)d_out;                                 // [H][N][N]
    float* outA   = (float*)d_out + (size_t)NH * NTOK * NTOK;      // [N][H*DH]

    // workspace (32 MB): Kw f32 8MB | Vw f32 8MB | A1 f32 8MB | Qbf bf16 4MB | Knbf bf16 4MB
    const size_t HND = (size_t)NH * NTOK * DH;
    float* Kw = (float*)d_ws;
    float* Vw = Kw + HND;
    float* A1 = Vw + HND;
    unsigned short* Qbf  = (unsigned short*)(A1 + HND);
    unsigned short* Knbf = Qbf + HND;

    proj_kernel<<<dim3(NTOK / 64, NH, 3), 256, 0, stream>>>(Q, K, V, Wq, Wk, Wv, Qbf, Kw, Vw);
    knorm_kernel<<<dim3(NH * NTOK / 4), 256, 0, stream>>>(Kw, Knbf);
    logits_mfma_kernel<<<dim3(NTOK / 64, NTOK / 64, NH), 256, 0, stream>>>(Qbf, Knbf, logits);
    attn_kernel<<<dim3(NTOK / 64, NH), 256, 0, stream>>>(logits, Vw, A1);
    outlin_kernel<<<dim3(NH * DH / 64, NTOK / 64), 256, 0, stream>>>(A1, W0, b0, outA);
}

// Round 4
// 555.335 us; speedup vs baseline: 1.5314x; 1.5314x over previous
//
#include <hip/hip_runtime.h>
#include <hip/hip_bf16.h>
#include <math.h>

#define NTOK 2048
#define DM   1024
#define NH   16
#define DH   64

typedef short bf16x8 __attribute__((ext_vector_type(8)));
typedef float f32x4  __attribute__((ext_vector_type(4)));

static __device__ __forceinline__ unsigned short f2bf(float x) {
    union { float f; unsigned u; } v; v.f = x;
    unsigned r = v.u + 0x7fff + ((v.u >> 16) & 1);   // round-to-nearest-even
    return (unsigned short)(r >> 16);
}

// ---------- castWt: W[h][d][c] f32 -> Wt[which][h][c][d] bf16 (transpose) ----------
__global__ __launch_bounds__(256) void castWt_kernel(
    const float* __restrict__ Wq, const float* __restrict__ Wk, const float* __restrict__ Wv,
    unsigned short* __restrict__ Wt)
{
    __shared__ float Ls[64][65];
    const int d0 = blockIdx.x * 64, h = blockIdx.y, which = blockIdx.z;
    const float* W = which == 0 ? Wq : (which == 1 ? Wk : Wv);
    const float* Wh = W + ((size_t)h * DM + d0) * DH;
    #pragma unroll
    for (int t = 0; t < 16; ++t) {
        int idx = threadIdx.x + t * 256; int r = idx >> 6, c = idx & 63;
        Ls[r][c] = Wh[(size_t)r * DH + c];
    }
    __syncthreads();
    unsigned short* Ot = Wt + ((size_t)(which * NH + h) * DH) * DM;
    #pragma unroll
    for (int t = 0; t < 16; ++t) {
        int idx = threadIdx.x + t * 256; int c = idx >> 6, r = idx & 63;
        Ot[(size_t)c * DM + d0 + r] = f2bf(Ls[r][c]);
    }
}

// ---------- castW0: W0[j][c] f32 -> bf16 same layout ----------
__global__ __launch_bounds__(256) void castW0_kernel(
    const float* __restrict__ W0, unsigned short* __restrict__ W0bf)
{
    int i = (blockIdx.x * 256 + threadIdx.x) * 4;
    float4 v = *(const float4*)(W0 + i);
    ushort4 u; u.x = f2bf(v.x); u.y = f2bf(v.y); u.z = f2bf(v.z); u.w = f2bf(v.w);
    *(ushort4*)(W0bf + i) = u;
}

// ---------- proj (MFMA): Xw[h,n,c] = sum_d X[n,d]*W[h,d,c]; K-branch fuses L2-normalize ----------
// wave = 16 n-rows x 64 c. A: X row frag (f32->bf16 in-reg); B: Wt[c][d] rows (contiguous).
// C/D: col=lane&15, row=(lane>>4)*4+i  [validated round 3].
__global__ __launch_bounds__(256) void proj_mfma_kernel(
    const float* __restrict__ Q, const float* __restrict__ K, const float* __restrict__ V,
    const unsigned short* __restrict__ Wt,
    unsigned short* __restrict__ Qbf, unsigned short* __restrict__ Knbf,
    unsigned short* __restrict__ Vwbf)
{
    const int which = blockIdx.z, h = blockIdx.y, n0 = blockIdx.x * 64;
    const int wave = threadIdx.x >> 6, lane = threadIdx.x & 63;
    const int lrow = lane & 15, kg = lane >> 4;
    const float* X = which == 0 ? Q : (which == 1 ? K : V);
    const unsigned short* Wth = Wt + ((size_t)(which * NH + h) * DH) * DM;
    const float* xrow = X + (size_t)(n0 + wave * 16 + lrow) * DM + kg * 8;

    f32x4 acc[4];
    #pragma unroll
    for (int mt = 0; mt < 4; ++mt) acc[mt] = (f32x4){0.f, 0.f, 0.f, 0.f};

    for (int d0 = 0; d0 < DM; d0 += 32) {
        float4 xa = *(const float4*)(xrow + d0);
        float4 xb = *(const float4*)(xrow + d0 + 4);
        bf16x8 a;
        a[0] = (short)f2bf(xa.x); a[1] = (short)f2bf(xa.y);
        a[2] = (short)f2bf(xa.z); a[3] = (short)f2bf(xa.w);
        a[4] = (short)f2bf(xb.x); a[5] = (short)f2bf(xb.y);
        a[6] = (short)f2bf(xb.z); a[7] = (short)f2bf(xb.w);
        #pragma unroll
        for (int mt = 0; mt < 4; ++mt) {
            bf16x8 b = *(const bf16x8*)(Wth + (size_t)(mt * 16 + lrow) * DM + d0 + kg * 8);
            acc[mt] = __builtin_amdgcn_mfma_f32_16x16x32_bf16(a, b, acc[mt], 0, 0, 0);
        }
    }

    if (which == 1) {
        // K: L2-normalize each row (64 cols spread over 4 mt x 16 lanes), write bf16
        #pragma unroll
        for (int i = 0; i < 4; ++i) {
            float ss = acc[0][i] * acc[0][i] + acc[1][i] * acc[1][i]
                     + acc[2][i] * acc[2][i] + acc[3][i] * acc[3][i];
            ss += __shfl_xor(ss, 1, 64); ss += __shfl_xor(ss, 2, 64);
            ss += __shfl_xor(ss, 4, 64); ss += __shfl_xor(ss, 8, 64);
            const float inv = 1.f / fmaxf(sqrtf(ss), 1e-12f);
            #pragma unroll
            for (int mt = 0; mt < 4; ++mt)
                Knbf[((size_t)h * NTOK + n0 + wave * 16 + kg * 4 + i) * DH + mt * 16 + lrow]
                    = f2bf(acc[mt][i] * inv);
        }
    } else {
        unsigned short* O = (which == 0) ? Qbf : Vwbf;
        #pragma unroll
        for (int i = 0; i < 4; ++i)
            #pragma unroll
            for (int mt = 0; mt < 4; ++mt)
                O[((size_t)h * NTOK + n0 + wave * 16 + kg * 4 + i) * DH + mt * 16 + lrow]
                    = f2bf(acc[mt][i]);
    }
}

// ---------- vtrans: Vwbf[h][n][k] -> Vt[h][k][n] ----------
__global__ __launch_bounds__(256) void vtrans_kernel(
    const unsigned short* __restrict__ Vwbf, unsigned short* __restrict__ Vt)
{
    __shared__ unsigned short Ls[64][73];   // odd-ish stride spreads banks
    const int n0 = blockIdx.x * 64, h = blockIdx.y;
    #pragma unroll
    for (int t = 0; t < 16; ++t) {
        int idx = threadIdx.x + t * 256; int r = idx >> 6, c = idx & 63;
        Ls[r][c] = Vwbf[((size_t)h * NTOK + n0 + r) * DH + c];
    }
    __syncthreads();
    #pragma unroll
    for (int t = 0; t < 16; ++t) {
        int idx = threadIdx.x + t * 256; int c = idx >> 6, r = idx & 63;
        Vt[((size_t)h * DH + c) * NTOK + n0 + r] = Ls[r][c];
    }
}

// ---------- fused attn: QK^T (MFMA) -> write logits -> online softmax -> PV (MFMA) ----------
// grid (h, nblk) h-major: head's K/V (512KB) pins to one XCD L2. No inter-wave sync.
__global__ __launch_bounds__(256) void fused_attn_kernel(
    const unsigned short* __restrict__ Qbf, const unsigned short* __restrict__ Knbf,
    const unsigned short* __restrict__ Vt, float* __restrict__ logits,
    unsigned short* __restrict__ A1bf)
{
    __shared__ unsigned short Pl[4][16][72];   // per-wave P; row stride 144B (16B-aligned)
    const int h = blockIdx.x, n0 = blockIdx.y * 64;
    const int wave = threadIdx.x >> 6, lane = threadIdx.x & 63;
    const int lrow = lane & 15, kg = lane >> 4;

    const unsigned short* qr = Qbf + ((size_t)h * NTOK + n0 + wave * 16 + lrow) * DH + kg * 8;
    const bf16x8 qa0 = *(const bf16x8*)qr;
    const bf16x8 qa1 = *(const bf16x8*)(qr + 32);
    const unsigned short* Kh = Knbf + (size_t)h * NTOK * DH;
    const unsigned short* Vh = Vt + (size_t)h * DH * NTOK;
    float* Lo = logits + ((size_t)h * NTOK + n0 + wave * 16) * NTOK;

    f32x4 o[4];
    #pragma unroll
    for (int kt = 0; kt < 4; ++kt) o[kt] = (f32x4){0.f, 0.f, 0.f, 0.f};
    float mr[4] = {-1e30f, -1e30f, -1e30f, -1e30f};
    float lr[4] = {0.f, 0.f, 0.f, 0.f};

    for (int m0 = 0; m0 < NTOK; m0 += 64) {
        f32x4 s[4];
        #pragma unroll
        for (int mt = 0; mt < 4; ++mt) {
            const unsigned short* kr = Kh + (size_t)(m0 + mt * 16 + lrow) * DH + kg * 8;
            bf16x8 b0 = *(const bf16x8*)kr;
            bf16x8 b1 = *(const bf16x8*)(kr + 32);
            f32x4 t = {0.f, 0.f, 0.f, 0.f};
            t = __builtin_amdgcn_mfma_f32_16x16x32_bf16(qa0, b0, t, 0, 0, 0);
            t = __builtin_amdgcn_mfma_f32_16x16x32_bf16(qa1, b1, t, 0, 0, 0);
            s[mt] = t;
        }
        // required output: pre-softmax logits (never re-read -> nontemporal)
        #pragma unroll
        for (int mt = 0; mt < 4; ++mt)
            #pragma unroll
            for (int i = 0; i < 4; ++i)
                __builtin_nontemporal_store(s[mt][i],
                    &Lo[(size_t)(kg * 4 + i) * NTOK + m0 + mt * 16 + lrow]);
        // online softmax per row (row = kg*4+i; 64 cols = 4 mt x 16 lanes)
        #pragma unroll
        for (int i = 0; i < 4; ++i) {
            float tm = fmaxf(fmaxf(s[0][i], s[1][i]), fmaxf(s[2][i], s[3][i]));
            tm = fmaxf(tm, __shfl_xor(tm, 1, 64)); tm = fmaxf(tm, __shfl_xor(tm, 2, 64));
            tm = fmaxf(tm, __shfl_xor(tm, 4, 64)); tm = fmaxf(tm, __shfl_xor(tm, 8, 64));
            const float nm = fmaxf(mr[i], tm);
            const float sc = __expf(mr[i] - nm);
            float p0 = __expf(s[0][i] - nm), p1 = __expf(s[1][i] - nm);
            float p2 = __expf(s[2][i] - nm), p3 = __expf(s[3][i] - nm);
            s[0][i] = p0; s[1][i] = p1; s[2][i] = p2; s[3][i] = p3;
            float ps = p0 + p1 + p2 + p3;
            ps += __shfl_xor(ps, 1, 64); ps += __shfl_xor(ps, 2, 64);
            ps += __shfl_xor(ps, 4, 64); ps += __shfl_xor(ps, 8, 64);
            lr[i] = lr[i] * sc + ps; mr[i] = nm;
            o[0][i] *= sc; o[1][i] *= sc; o[2][i] *= sc; o[3][i] *= sc;
        }
        // P: C/D layout -> LDS -> A layout (per-wave private, wave-synchronous)
        #pragma unroll
        for (int mt = 0; mt < 4; ++mt)
            #pragma unroll
            for (int i = 0; i < 4; ++i)
                Pl[wave][kg * 4 + i][mt * 16 + lrow] = f2bf(s[mt][i]);
        asm volatile("s_waitcnt lgkmcnt(0)" ::: "memory");
        __builtin_amdgcn_sched_barrier(0);
        bf16x8 pa0 = *(const bf16x8*)&Pl[wave][lrow][kg * 8];
        bf16x8 pa1 = *(const bf16x8*)&Pl[wave][lrow][32 + kg * 8];
        #pragma unroll
        for (int kt = 0; kt < 4; ++kt) {
            const unsigned short* vr = Vh + (size_t)(kt * 16 + lrow) * NTOK + m0 + kg * 8;
            bf16x8 v0 = *(const bf16x8*)vr;
            bf16x8 v1 = *(const bf16x8*)(vr + 32);
            o[kt] = __builtin_amdgcn_mfma_f32_16x16x32_bf16(pa0, v0, o[kt], 0, 0, 0);
            o[kt] = __builtin_amdgcn_mfma_f32_16x16x32_bf16(pa1, v1, o[kt], 0, 0, 0);
        }
    }
    #pragma unroll
    for (int i = 0; i < 4; ++i) {
        const float inv = 1.f / lr[i];
        #pragma unroll
        for (int kt = 0; kt < 4; ++kt)
            A1bf[(size_t)(n0 + wave * 16 + kg * 4 + i) * (NH * DH) + h * DH + kt * 16 + lrow]
                = f2bf(o[kt][i] * inv);
    }
}

// ---------- outlin (MFMA): out[n,j] = sum_c A1[n,c]*W0[j,c] + b0[j] ----------
__global__ __launch_bounds__(256) void outlin_mfma_kernel(
    const unsigned short* __restrict__ A1bf, const unsigned short* __restrict__ W0bf,
    const float* __restrict__ b0, float* __restrict__ outA)
{
    const int j0 = blockIdx.x * 64, n0 = blockIdx.y * 64;
    const int wave = threadIdx.x >> 6, lane = threadIdx.x & 63;
    const int lrow = lane & 15, kg = lane >> 4;
    const unsigned short* ar = A1bf + (size_t)(n0 + wave * 16 + lrow) * (NH * DH);

    f32x4 acc[4];
    #pragma unroll
    for (int jt = 0; jt < 4; ++jt) acc[jt] = (f32x4){0.f, 0.f, 0.f, 0.f};

    for (int c0 = 0; c0 < NH * DH; c0 += 32) {
        bf16x8 a = *(const bf16x8*)(ar + c0 + kg * 8);
        #pragma unroll
        for (int jt = 0; jt < 4; ++jt) {
            bf16x8 b = *(const bf16x8*)(W0bf + (size_t)(j0 + jt * 16 + lrow) * (NH * DH) + c0 + kg * 8);
            acc[jt] = __builtin_amdgcn_mfma_f32_16x16x32_bf16(a, b, acc[jt], 0, 0, 0);
        }
    }
    #pragma unroll
    for (int jt = 0; jt < 4; ++jt) {
        const float bb = b0[j0 + jt * 16 + lrow];
        #pragma unroll
        for (int i = 0; i < 4; ++i)
            outA[(size_t)(n0 + wave * 16 + kg * 4 + i) * (NH * DH) + j0 + jt * 16 + lrow]
                = acc[jt][i] + bb;
    }
}

extern "C" void kernel_launch(void* const* d_in, const int* in_sizes, int n_in,
                              void* d_out, int out_size, void* d_ws, size_t ws_size,
                              hipStream_t stream)
{
    const float* Q  = (const float*)d_in[0];
    const float* K  = (const float*)d_in[1];
    const float* V  = (const float*)d_in[2];
    const float* Wq = (const float*)d_in[3];
    const float* Wk = (const float*)d_in[4];
    const float* Wv = (const float*)d_in[5];
    const float* W0 = (const float*)d_in[6];
    const float* b0 = (const float*)d_in[7];

    float* logits = (float*)d_out;                                 // [H][N][N]
    float* outA   = (float*)d_out + (size_t)NH * NTOK * NTOK;      // [N][H*DH]

    // ws layout (28 MB total, all fully rewritten every call):
    char* p = (char*)d_ws;
    unsigned short* Wt   = (unsigned short*)p;             p += (size_t)3 * NH * DH * DM * 2;  // 6.29 MB
    unsigned short* W0bf = (unsigned short*)p;             p += (size_t)DM * DM * 2;           // 2.10 MB
    unsigned short* Qbf  = (unsigned short*)p;             p += (size_t)NH * NTOK * DH * 2;    // 4.19 MB
    unsigned short* Knbf = (unsigned short*)p;             p += (size_t)NH * NTOK * DH * 2;
    unsigned short* Vwbf = (unsigned short*)p;             p += (size_t)NH * NTOK * DH * 2;
    unsigned short* Vt   = (unsigned short*)p;             p += (size_t)NH * NTOK * DH * 2;
    unsigned short* A1bf = (unsigned short*)p;

    castWt_kernel   <<<dim3(DM / 64, NH, 3), 256, 0, stream>>>(Wq, Wk, Wv, Wt);
    castW0_kernel   <<<dim3(DM * DM / 1024), 256, 0, stream>>>(W0, W0bf);
    proj_mfma_kernel<<<dim3(NTOK / 64, NH, 3), 256, 0, stream>>>(Q, K, V, Wt, Qbf, Knbf, Vwbf);
    vtrans_kernel   <<<dim3(NTOK / 64, NH), 256, 0, stream>>>(Vwbf, Vt);
    fused_attn_kernel<<<dim3(NH, NTOK / 64), 256, 0, stream>>>(Qbf, Knbf, Vt, logits, A1bf);
    outlin_mfma_kernel<<<dim3(NH * DH / 64, NTOK / 64), 256, 0, stream>>>(A1bf, W0bf, b0, outA);
}

// Round 6
// 544.351 us; speedup vs baseline: 1.5623x; 1.0202x over previous
//
#include <hip/hip_runtime.h>
#include <hip/hip_bf16.h>
#include <math.h>

#define NTOK 2048
#define DM   1024
#define NH   16
#define DH   64

typedef short bf16x8 __attribute__((ext_vector_type(8)));
typedef float f32x4  __attribute__((ext_vector_type(4)));

static __device__ __forceinline__ unsigned short f2bf(float x) {
    union { float f; unsigned u; } v; v.f = x;
    unsigned r = v.u + 0x7fff + ((v.u >> 16) & 1);   // round-to-nearest-even
    return (unsigned short)(r >> 16);
}

// ---------- castX: Q/K/V f32 -> Xbf[which][n][d] bf16 ----------
__global__ __launch_bounds__(256) void castX_kernel(
    const float* __restrict__ Q, const float* __restrict__ K, const float* __restrict__ V,
    unsigned short* __restrict__ Xbf)
{
    const int which = blockIdx.y;
    const float* src = which == 0 ? Q : (which == 1 ? K : V);
    const size_t T = (size_t)NTOK * DM;
    size_t i = ((size_t)blockIdx.x * 256 + threadIdx.x) * 8;
    float4 a = *(const float4*)(src + i);
    float4 b = *(const float4*)(src + i + 4);
    ushort4 u0, u1;
    u0.x = f2bf(a.x); u0.y = f2bf(a.y); u0.z = f2bf(a.z); u0.w = f2bf(a.w);
    u1.x = f2bf(b.x); u1.y = f2bf(b.y); u1.z = f2bf(b.z); u1.w = f2bf(b.w);
    unsigned short* dst = Xbf + which * T + i;
    *(ushort4*)(dst)     = u0;
    *(ushort4*)(dst + 4) = u1;
}

// ---------- castWt: W[h][d][c] f32 -> Wt[which][h][c][d] bf16 (transpose) ----------
__global__ __launch_bounds__(256) void castWt_kernel(
    const float* __restrict__ Wq, const float* __restrict__ Wk, const float* __restrict__ Wv,
    unsigned short* __restrict__ Wt)
{
    __shared__ float Ls[64][65];
    const int d0 = blockIdx.x * 64, h = blockIdx.y, which = blockIdx.z;
    const float* W = which == 0 ? Wq : (which == 1 ? Wk : Wv);
    const float* Wh = W + ((size_t)h * DM + d0) * DH;
    #pragma unroll
    for (int t = 0; t < 16; ++t) {
        int idx = threadIdx.x + t * 256; int r = idx >> 6, c = idx & 63;
        Ls[r][c] = Wh[(size_t)r * DH + c];
    }
    __syncthreads();
    unsigned short* Ot = Wt + ((size_t)(which * NH + h) * DH) * DM;
    #pragma unroll
    for (int t = 0; t < 16; ++t) {
        int idx = threadIdx.x + t * 256; int c = idx >> 6, r = idx & 63;
        Ot[(size_t)c * DM + d0 + r] = f2bf(Ls[r][c]);
    }
}

// ---------- castW0: W0[j][c] f32 -> bf16 same layout ----------
__global__ __launch_bounds__(256) void castW0_kernel(
    const float* __restrict__ W0, unsigned short* __restrict__ W0bf)
{
    int i = (blockIdx.x * 256 + threadIdx.x) * 4;
    float4 v = *(const float4*)(W0 + i);
    ushort4 u; u.x = f2bf(v.x); u.y = f2bf(v.y); u.z = f2bf(v.z); u.w = f2bf(v.w);
    *(ushort4*)(W0bf + i) = u;
}

// ---------- proj (MFMA, bf16 A): Xw[h,n,c] = sum_d X[n,d]*W[h,d,c]; K fuses L2-norm ----------
__global__ __launch_bounds__(256) void proj_mfma_kernel(
    const unsigned short* __restrict__ Xbf, const unsigned short* __restrict__ Wt,
    unsigned short* __restrict__ Qbf, unsigned short* __restrict__ Knbf,
    unsigned short* __restrict__ Vwbf)
{
    const int which = blockIdx.z, h = blockIdx.y, n0 = blockIdx.x * 64;
    const int wave = threadIdx.x >> 6, lane = threadIdx.x & 63;
    const int lrow = lane & 15, kg = lane >> 4;
    const unsigned short* Wth = Wt + ((size_t)(which * NH + h) * DH) * DM;
    const unsigned short* xrow = Xbf + (size_t)which * NTOK * DM
                               + (size_t)(n0 + wave * 16 + lrow) * DM + kg * 8;

    f32x4 acc[4];
    #pragma unroll
    for (int mt = 0; mt < 4; ++mt) acc[mt] = (f32x4){0.f, 0.f, 0.f, 0.f};

    for (int d0 = 0; d0 < DM; d0 += 32) {
        bf16x8 a = *(const bf16x8*)(xrow + d0);
        #pragma unroll
        for (int mt = 0; mt < 4; ++mt) {
            bf16x8 b = *(const bf16x8*)(Wth + (size_t)(mt * 16 + lrow) * DM + d0 + kg * 8);
            acc[mt] = __builtin_amdgcn_mfma_f32_16x16x32_bf16(a, b, acc[mt], 0, 0, 0);
        }
    }

    if (which == 1) {
        #pragma unroll
        for (int i = 0; i < 4; ++i) {
            float ss = acc[0][i] * acc[0][i] + acc[1][i] * acc[1][i]
                     + acc[2][i] * acc[2][i] + acc[3][i] * acc[3][i];
            ss += __shfl_xor(ss, 1, 64); ss += __shfl_xor(ss, 2, 64);
            ss += __shfl_xor(ss, 4, 64); ss += __shfl_xor(ss, 8, 64);
            const float inv = 1.f / fmaxf(sqrtf(ss), 1e-12f);
            #pragma unroll
            for (int mt = 0; mt < 4; ++mt)
                Knbf[((size_t)h * NTOK + n0 + wave * 16 + kg * 4 + i) * DH + mt * 16 + lrow]
                    = f2bf(acc[mt][i] * inv);
        }
    } else {
        unsigned short* O = (which == 0) ? Qbf : Vwbf;
        #pragma unroll
        for (int i = 0; i < 4; ++i)
            #pragma unroll
            for (int mt = 0; mt < 4; ++mt)
                O[((size_t)h * NTOK + n0 + wave * 16 + kg * 4 + i) * DH + mt * 16 + lrow]
                    = f2bf(acc[mt][i]);
    }
}

// ---------- vtrans: Vwbf[h][n][k] -> Vt[h][k][n] ----------
__global__ __launch_bounds__(256) void vtrans_kernel(
    const unsigned short* __restrict__ Vwbf, unsigned short* __restrict__ Vt)
{
    __shared__ unsigned short Ls[64][73];
    const int n0 = blockIdx.x * 64, h = blockIdx.y;
    #pragma unroll
    for (int t = 0; t < 16; ++t) {
        int idx = threadIdx.x + t * 256; int r = idx >> 6, c = idx & 63;
        Ls[r][c] = Vwbf[((size_t)h * NTOK + n0 + r) * DH + c];
    }
    __syncthreads();
    #pragma unroll
    for (int t = 0; t < 16; ++t) {
        int idx = threadIdx.x + t * 256; int c = idx >> 6, r = idx & 63;
        Vt[((size_t)h * DH + c) * NTOK + n0 + r] = Ls[r][c];
    }
}

// ---------- fused attn v2: QK^T -> coalesced logits -> no-max softmax -> PV ----------
// grid (h, nblk) h-major: head's K/V pins to one XCD L2. No inter-wave sync.
// Per tile: V loads issued first (overlap QK/softmax); K-frags for tile t+1 prefetched
// cross-tile via ping-pong regs (manual 2x unroll). Logits go through Sl LDS transpose
// so stores are f32x4 at 4x256B segments per instruction.
#define ATTN_TILE(M0, KC0, KC1, KN0, KN1)                                          \
  {                                                                                \
    const int mb = (M0);                                                           \
    bf16x8 vb0[4], vb1[4];                                                         \
    _Pragma("unroll")                                                              \
    for (int kt = 0; kt < 4; ++kt) {                                               \
      const unsigned short* vr = Vh + (size_t)(kt * 16 + lrow) * NTOK + mb + kg * 8; \
      vb0[kt] = *(const bf16x8*)vr; vb1[kt] = *(const bf16x8*)(vr + 32);           \
    }                                                                              \
    f32x4 s[4];                                                                    \
    _Pragma("unroll")                                                              \
    for (int mt = 0; mt < 4; ++mt) {                                               \
      f32x4 t = {0.f, 0.f, 0.f, 0.f};                                              \
      t = __builtin_amdgcn_mfma_f32_16x16x32_bf16(qa0, KC0[mt], t, 0, 0, 0);        \
      t = __builtin_amdgcn_mfma_f32_16x16x32_bf16(qa1, KC1[mt], t, 0, 0, 0);        \
      s[mt] = t;                                                                   \
    }                                                                              \
    const int mnx = (mb + 64) & (NTOK - 1);                                        \
    _Pragma("unroll")                                                              \
    for (int mt = 0; mt < 4; ++mt) {                                               \
      const unsigned short* kr = Kh + (size_t)(mnx + mt * 16 + lrow) * DH + kg * 8; \
      KN0[mt] = *(const bf16x8*)kr; KN1[mt] = *(const bf16x8*)(kr + 32);           \
    }                                                                              \
    _Pragma("unroll")                                                              \
    for (int mt = 0; mt < 4; ++mt)                                                 \
      _Pragma("unroll")                                                            \
      for (int i = 0; i < 4; ++i)                                                  \
        Sl[wave][kg * 4 + i][mt * 16 + lrow] = s[mt][i];                           \
    _Pragma("unroll")                                                              \
    for (int i = 0; i < 4; ++i) {                                                  \
      f32x4 r4 = *(const f32x4*)&Sl[wave][i * 4 + kg][(lane & 15) * 4];            \
      __builtin_nontemporal_store(r4,                                              \
          (f32x4*)&Lo[(size_t)(i * 4 + kg) * NTOK + mb + (lane & 15) * 4]);        \
    }                                                                              \
    _Pragma("unroll")                                                              \
    for (int mt = 0; mt < 4; ++mt)                                                 \
      _Pragma("unroll")                                                            \
      for (int i = 0; i < 4; ++i) s[mt][i] = __expf(s[mt][i]);                     \
    _Pragma("unroll")                                                              \
    for (int i = 0; i < 4; ++i)                                                    \
      lrp[i] += s[0][i] + s[1][i] + s[2][i] + s[3][i];                             \
    _Pragma("unroll")                                                              \
    for (int mt = 0; mt < 4; ++mt)                                                 \
      _Pragma("unroll")                                                            \
      for (int i = 0; i < 4; ++i)                                                  \
        Pl[wave][kg * 4 + i][mt * 16 + lrow] = f2bf(s[mt][i]);                     \
    asm volatile("s_waitcnt lgkmcnt(0)" ::: "memory");                             \
    __builtin_amdgcn_sched_barrier(0);                                             \
    {                                                                              \
      bf16x8 pa0 = *(const bf16x8*)&Pl[wave][lrow][kg * 8];                        \
      bf16x8 pa1 = *(const bf16x8*)&Pl[wave][lrow][32 + kg * 8];                   \
      _Pragma("unroll")                                                            \
      for (int kt = 0; kt < 4; ++kt) {                                             \
        o[kt] = __builtin_amdgcn_mfma_f32_16x16x32_bf16(pa0, vb0[kt], o[kt], 0, 0, 0); \
        o[kt] = __builtin_amdgcn_mfma_f32_16x16x32_bf16(pa1, vb1[kt], o[kt], 0, 0, 0); \
      }                                                                            \
    }                                                                              \
  }

__global__ __launch_bounds__(256) void fused_attn_kernel(
    const unsigned short* __restrict__ Qbf, const unsigned short* __restrict__ Knbf,
    const unsigned short* __restrict__ Vt, float* __restrict__ logits,
    unsigned short* __restrict__ A1bf)
{
    __shared__ float Sl[4][16][68];            // per-wave S transpose (f32)
    __shared__ unsigned short Pl[4][16][72];   // per-wave P (bf16), 16B-aligned rows
    const int h = blockIdx.x, n0 = blockIdx.y * 64;
    const int wave = threadIdx.x >> 6, lane = threadIdx.x & 63;
    const int lrow = lane & 15, kg = lane >> 4;

    const unsigned short* qr = Qbf + ((size_t)h * NTOK + n0 + wave * 16 + lrow) * DH + kg * 8;
    const bf16x8 qa0 = *(const bf16x8*)qr;
    const bf16x8 qa1 = *(const bf16x8*)(qr + 32);
    const unsigned short* Kh = Knbf + (size_t)h * NTOK * DH;
    const unsigned short* Vh = Vt + (size_t)h * DH * NTOK;
    float* Lo = logits + ((size_t)h * NTOK + n0 + wave * 16) * NTOK;

    f32x4 o[4];
    #pragma unroll
    for (int kt = 0; kt < 4; ++kt) o[kt] = (f32x4){0.f, 0.f, 0.f, 0.f};
    float lrp[4] = {0.f, 0.f, 0.f, 0.f};   // in-lane partial row sums

    bf16x8 kA0[4], kA1[4], kB0[4], kB1[4];
    #pragma unroll
    for (int mt = 0; mt < 4; ++mt) {
        const unsigned short* kr = Kh + (size_t)(mt * 16 + lrow) * DH + kg * 8;
        kA0[mt] = *(const bf16x8*)kr; kA1[mt] = *(const bf16x8*)(kr + 32);
    }

    for (int m0 = 0; m0 < NTOK; m0 += 128) {
        ATTN_TILE(m0,      kA0, kA1, kB0, kB1);
        ATTN_TILE(m0 + 64, kB0, kB1, kA0, kA1);
    }

    #pragma unroll
    for (int i = 0; i < 4; ++i) {
        float t = lrp[i];
        t += __shfl_xor(t, 1, 64); t += __shfl_xor(t, 2, 64);
        t += __shfl_xor(t, 4, 64); t += __shfl_xor(t, 8, 64);
        const float inv = 1.f / t;
        #pragma unroll
        for (int kt = 0; kt < 4; ++kt)
            A1bf[(size_t)(n0 + wave * 16 + kg * 4 + i) * (NH * DH) + h * DH + kt * 16 + lrow]
                = f2bf(o[kt][i] * inv);
    }
}

// ---------- outlin (MFMA): out[n,j] = sum_c A1[n,c]*W0[j,c] + b0[j] ----------
__global__ __launch_bounds__(256) void outlin_mfma_kernel(
    const unsigned short* __restrict__ A1bf, const unsigned short* __restrict__ W0bf,
    const float* __restrict__ b0, float* __restrict__ outA)
{
    const int j0 = blockIdx.x * 64, n0 = blockIdx.y * 64;
    const int wave = threadIdx.x >> 6, lane = threadIdx.x & 63;
    const int lrow = lane & 15, kg = lane >> 4;
    const unsigned short* ar = A1bf + (size_t)(n0 + wave * 16 + lrow) * (NH * DH);

    f32x4 acc[4];
    #pragma unroll
    for (int jt = 0; jt < 4; ++jt) acc[jt] = (f32x4){0.f, 0.f, 0.f, 0.f};

    for (int c0 = 0; c0 < NH * DH; c0 += 32) {
        bf16x8 a = *(const bf16x8*)(ar + c0 + kg * 8);
        #pragma unroll
        for (int jt = 0; jt < 4; ++jt) {
            bf16x8 b = *(const bf16x8*)(W0bf + (size_t)(j0 + jt * 16 + lrow) * (NH * DH) + c0 + kg * 8);
            acc[jt] = __builtin_amdgcn_mfma_f32_16x16x32_bf16(a, b, acc[jt], 0, 0, 0);
        }
    }
    #pragma unroll
    for (int jt = 0; jt < 4; ++jt) {
        const float bb = b0[j0 + jt * 16 + lrow];
        #pragma unroll
        for (int i = 0; i < 4; ++i)
            outA[(size_t)(n0 + wave * 16 + kg * 4 + i) * (NH * DH) + j0 + jt * 16 + lrow]
                = acc[jt][i] + bb;
    }
}

extern "C" void kernel_launch(void* const* d_in, const int* in_sizes, int n_in,
                              void* d_out, int out_size, void* d_ws, size_t ws_size,
                              hipStream_t stream)
{
    const float* Q  = (const float*)d_in[0];
    const float* K  = (const float*)d_in[1];
    const float* V  = (const float*)d_in[2];
    const float* Wq = (const float*)d_in[3];
    const float* Wk = (const float*)d_in[4];
    const float* Wv = (const float*)d_in[5];
    const float* W0 = (const float*)d_in[6];
    const float* b0 = (const float*)d_in[7];

    float* logits = (float*)d_out;                                 // [H][N][N]
    float* outA   = (float*)d_out + (size_t)NH * NTOK * NTOK;      // [N][H*DH]

    // ws layout (~42 MB), all fully rewritten each call:
    char* p = (char*)d_ws;
    unsigned short* Wt   = (unsigned short*)p;  p += (size_t)3 * NH * DH * DM * 2;   // 6.29 MB
    unsigned short* W0bf = (unsigned short*)p;  p += (size_t)DM * DM * 2;            // 2.10 MB
    unsigned short* Qbf  = (unsigned short*)p;  p += (size_t)NH * NTOK * DH * 2;     // 4.19 MB
    unsigned short* Knbf = (unsigned short*)p;  p += (size_t)NH * NTOK * DH * 2;
    unsigned short* Vwbf = (unsigned short*)p;  p += (size_t)NH * NTOK * DH * 2;
    unsigned short* Vt   = (unsigned short*)p;  p += (size_t)NH * NTOK * DH * 2;
    unsigned short* A1bf = (unsigned short*)p;  p += (size_t)NH * NTOK * DH * 2;
    unsigned short* Xbf  = (unsigned short*)p;                                        // 12.58 MB

    castX_kernel    <<<dim3(NTOK * DM / (256 * 8), 3), 256, 0, stream>>>(Q, K, V, Xbf);
    castWt_kernel   <<<dim3(DM / 64, NH, 3), 256, 0, stream>>>(Wq, Wk, Wv, Wt);
    castW0_kernel   <<<dim3(DM * DM / 1024), 256, 0, stream>>>(W0, W0bf);
    proj_mfma_kernel<<<dim3(NTOK / 64, NH, 3), 256, 0, stream>>>(Xbf, Wt, Qbf, Knbf, Vwbf);
    vtrans_kernel   <<<dim3(NTOK / 64, NH), 256, 0, stream>>>(Vwbf, Vt);
    fused_attn_kernel<<<dim3(NH, NTOK / 64), 256, 0, stream>>>(Qbf, Knbf, Vt, logits, A1bf);
    outlin_mfma_kernel<<<dim3(NH * DH / 64, NTOK / 64), 256, 0, stream>>>(A1bf, W0bf, b0, outA);
}

// Round 8
// 543.909 us; speedup vs baseline: 1.5636x; 1.0008x over previous
//
#include <hip/hip_runtime.h>
#include <hip/hip_bf16.h>
#include <math.h>

#define NTOK 2048
#define DM   1024
#define NH   16
#define DH   64
#define SPLIT 4
#define MSPL (NTOK / SPLIT)   // 512 k-tokens per split

typedef short bf16x8 __attribute__((ext_vector_type(8)));
typedef float f32x4  __attribute__((ext_vector_type(4)));

static __device__ __forceinline__ unsigned short f2bf(float x) {
    union { float f; unsigned u; } v; v.f = x;
    unsigned r = v.u + 0x7fff + ((v.u >> 16) & 1);   // round-to-nearest-even
    return (unsigned short)(r >> 16);
}
static __device__ __forceinline__ float bf2f(unsigned short b) {
    union { unsigned u; float f; } v; v.u = ((unsigned)b) << 16; return v.f;
}

// ---------- castX: Q/K/V f32 -> Xbf[which][n][d] bf16 ----------
__global__ __launch_bounds__(256) void castX_kernel(
    const float* __restrict__ Q, const float* __restrict__ K, const float* __restrict__ V,
    unsigned short* __restrict__ Xbf)
{
    const int which = blockIdx.y;
    const float* src = which == 0 ? Q : (which == 1 ? K : V);
    const size_t T = (size_t)NTOK * DM;
    size_t i = ((size_t)blockIdx.x * 256 + threadIdx.x) * 8;
    float4 a = *(const float4*)(src + i);
    float4 b = *(const float4*)(src + i + 4);
    ushort4 u0, u1;
    u0.x = f2bf(a.x); u0.y = f2bf(a.y); u0.z = f2bf(a.z); u0.w = f2bf(a.w);
    u1.x = f2bf(b.x); u1.y = f2bf(b.y); u1.z = f2bf(b.z); u1.w = f2bf(b.w);
    unsigned short* dst = Xbf + which * T + i;
    *(ushort4*)(dst)     = u0;
    *(ushort4*)(dst + 4) = u1;
}

// ---------- castWt: W[h][d][c] f32 -> Wt[which][h][c][d] bf16 (transpose) ----------
__global__ __launch_bounds__(256) void castWt_kernel(
    const float* __restrict__ Wq, const float* __restrict__ Wk, const float* __restrict__ Wv,
    unsigned short* __restrict__ Wt)
{
    __shared__ float Ls[64][65];
    const int d0 = blockIdx.x * 64, h = blockIdx.y, which = blockIdx.z;
    const float* W = which == 0 ? Wq : (which == 1 ? Wk : Wv);
    const float* Wh = W + ((size_t)h * DM + d0) * DH;
    #pragma unroll
    for (int t = 0; t < 16; ++t) {
        int idx = threadIdx.x + t * 256; int r = idx >> 6, c = idx & 63;
        Ls[r][c] = Wh[(size_t)r * DH + c];
    }
    __syncthreads();
    unsigned short* Ot = Wt + ((size_t)(which * NH + h) * DH) * DM;
    #pragma unroll
    for (int t = 0; t < 16; ++t) {
        int idx = threadIdx.x + t * 256; int c = idx >> 6, r = idx & 63;
        Ot[(size_t)c * DM + d0 + r] = f2bf(Ls[r][c]);
    }
}

// ---------- castW0: W0[j][c] f32 -> bf16 same layout ----------
__global__ __launch_bounds__(256) void castW0_kernel(
    const float* __restrict__ W0, unsigned short* __restrict__ W0bf)
{
    int i = (blockIdx.x * 256 + threadIdx.x) * 4;
    float4 v = *(const float4*)(W0 + i);
    ushort4 u; u.x = f2bf(v.x); u.y = f2bf(v.y); u.z = f2bf(v.z); u.w = f2bf(v.w);
    *(ushort4*)(W0bf + i) = u;
}

// ---------- proj (MFMA): Q->Qbf, K->Knbf (L2-norm fused), V->Vt (direct transpose) ----------
__global__ __launch_bounds__(256) void proj_mfma_kernel(
    const unsigned short* __restrict__ Xbf, const unsigned short* __restrict__ Wt,
    unsigned short* __restrict__ Qbf, unsigned short* __restrict__ Knbf,
    unsigned short* __restrict__ Vt)
{
    const int which = blockIdx.z, h = blockIdx.y, n0 = blockIdx.x * 64;
    const int wave = threadIdx.x >> 6, lane = threadIdx.x & 63;
    const int lrow = lane & 15, kg = lane >> 4;
    const unsigned short* Wth = Wt + ((size_t)(which * NH + h) * DH) * DM;
    const unsigned short* xrow = Xbf + (size_t)which * NTOK * DM
                               + (size_t)(n0 + wave * 16 + lrow) * DM + kg * 8;

    f32x4 acc[4];
    #pragma unroll
    for (int mt = 0; mt < 4; ++mt) acc[mt] = (f32x4){0.f, 0.f, 0.f, 0.f};

    for (int d0 = 0; d0 < DM; d0 += 32) {
        bf16x8 a = *(const bf16x8*)(xrow + d0);
        #pragma unroll
        for (int mt = 0; mt < 4; ++mt) {
            bf16x8 b = *(const bf16x8*)(Wth + (size_t)(mt * 16 + lrow) * DM + d0 + kg * 8);
            acc[mt] = __builtin_amdgcn_mfma_f32_16x16x32_bf16(a, b, acc[mt], 0, 0, 0);
        }
    }

    if (which == 1) {
        #pragma unroll
        for (int i = 0; i < 4; ++i) {
            float ss = acc[0][i] * acc[0][i] + acc[1][i] * acc[1][i]
                     + acc[2][i] * acc[2][i] + acc[3][i] * acc[3][i];
            ss += __shfl_xor(ss, 1, 64); ss += __shfl_xor(ss, 2, 64);
            ss += __shfl_xor(ss, 4, 64); ss += __shfl_xor(ss, 8, 64);
            const float inv = 1.f / fmaxf(sqrtf(ss), 1e-12f);
            #pragma unroll
            for (int mt = 0; mt < 4; ++mt)
                Knbf[((size_t)h * NTOK + n0 + wave * 16 + kg * 4 + i) * DH + mt * 16 + lrow]
                    = f2bf(acc[mt][i] * inv);
        }
    } else if (which == 0) {
        #pragma unroll
        for (int i = 0; i < 4; ++i)
            #pragma unroll
            for (int mt = 0; mt < 4; ++mt)
                Qbf[((size_t)h * NTOK + n0 + wave * 16 + kg * 4 + i) * DH + mt * 16 + lrow]
                    = f2bf(acc[mt][i]);
    } else {
        // V: write transposed Vt[h][c][n]; acc[mt][i] is (row n=+kg*4+i, col c=mt*16+lrow)
        #pragma unroll
        for (int mt = 0; mt < 4; ++mt) {
            ushort4 u;
            u.x = f2bf(acc[mt][0]); u.y = f2bf(acc[mt][1]);
            u.z = f2bf(acc[mt][2]); u.w = f2bf(acc[mt][3]);
            *(ushort4*)&Vt[((size_t)h * DH + mt * 16 + lrow) * NTOK + n0 + wave * 16 + kg * 4] = u;
        }
    }
}

// ---------- fused attn (split-m): QK^T -> logits -> no-max softmax -> PV partials ----------
// grid (h, nblk, split): 2048 blocks x 4 waves = 8192 waves. No inter-wave sync.
__global__ __launch_bounds__(256, 4) void fused_attn_kernel(
    const unsigned short* __restrict__ Qbf, const unsigned short* __restrict__ Knbf,
    const unsigned short* __restrict__ Vt, float* __restrict__ logits,
    unsigned short* __restrict__ opart, float* __restrict__ lpart)
{
    __shared__ float Sl[4][16][68];            // per-wave S transpose (f32)
    __shared__ unsigned short Pl[4][16][72];   // per-wave P (bf16), 16B-aligned rows
    const int h = blockIdx.x, n0 = blockIdx.y * 64, sp = blockIdx.z;
    const int wave = threadIdx.x >> 6, lane = threadIdx.x & 63;
    const int lrow = lane & 15, kg = lane >> 4;

    const unsigned short* qr = Qbf + ((size_t)h * NTOK + n0 + wave * 16 + lrow) * DH + kg * 8;
    const bf16x8 qa0 = *(const bf16x8*)qr;
    const bf16x8 qa1 = *(const bf16x8*)(qr + 32);
    const unsigned short* Kh = Knbf + (size_t)h * NTOK * DH;
    const unsigned short* Vh = Vt + (size_t)h * DH * NTOK;
    float* Lo = logits + ((size_t)h * NTOK + n0 + wave * 16) * NTOK;

    f32x4 o[4];
    #pragma unroll
    for (int kt = 0; kt < 4; ++kt) o[kt] = (f32x4){0.f, 0.f, 0.f, 0.f};
    float lrp[4] = {0.f, 0.f, 0.f, 0.f};

    for (int mb = sp * MSPL; mb < sp * MSPL + MSPL; mb += 64) {
        // V fragments first (independent; overlap QK below)
        bf16x8 vb0[4], vb1[4];
        #pragma unroll
        for (int kt = 0; kt < 4; ++kt) {
            const unsigned short* vr = Vh + (size_t)(kt * 16 + lrow) * NTOK + mb + kg * 8;
            vb0[kt] = *(const bf16x8*)vr; vb1[kt] = *(const bf16x8*)(vr + 32);
        }
        // QK^T
        f32x4 s[4];
        #pragma unroll
        for (int mt = 0; mt < 4; ++mt) {
            const unsigned short* kr = Kh + (size_t)(mb + mt * 16 + lrow) * DH + kg * 8;
            bf16x8 kb0 = *(const bf16x8*)kr;
            bf16x8 kb1 = *(const bf16x8*)(kr + 32);
            f32x4 t = {0.f, 0.f, 0.f, 0.f};
            t = __builtin_amdgcn_mfma_f32_16x16x32_bf16(qa0, kb0, t, 0, 0, 0);
            t = __builtin_amdgcn_mfma_f32_16x16x32_bf16(qa1, kb1, t, 0, 0, 0);
            s[mt] = t;
        }
        // coalesced logits store via per-wave LDS transpose
        #pragma unroll
        for (int mt = 0; mt < 4; ++mt)
            #pragma unroll
            for (int i = 0; i < 4; ++i)
                Sl[wave][kg * 4 + i][mt * 16 + lrow] = s[mt][i];
        #pragma unroll
        for (int i = 0; i < 4; ++i) {
            f32x4 r4 = *(const f32x4*)&Sl[wave][i * 4 + kg][lrow * 4];
            __builtin_nontemporal_store(r4,
                (f32x4*)&Lo[(size_t)(i * 4 + kg) * NTOK + mb + lrow * 4]);
        }
        // no-max softmax partials
        #pragma unroll
        for (int mt = 0; mt < 4; ++mt)
            #pragma unroll
            for (int i = 0; i < 4; ++i) s[mt][i] = __expf(s[mt][i]);
        #pragma unroll
        for (int i = 0; i < 4; ++i)
            lrp[i] += s[0][i] + s[1][i] + s[2][i] + s[3][i];
        #pragma unroll
        for (int mt = 0; mt < 4; ++mt)
            #pragma unroll
            for (int i = 0; i < 4; ++i)
                Pl[wave][kg * 4 + i][mt * 16 + lrow] = f2bf(s[mt][i]);
        asm volatile("s_waitcnt lgkmcnt(0)" ::: "memory");
        __builtin_amdgcn_sched_barrier(0);
        {
            bf16x8 pa0 = *(const bf16x8*)&Pl[wave][lrow][kg * 8];
            bf16x8 pa1 = *(const bf16x8*)&Pl[wave][lrow][32 + kg * 8];
            #pragma unroll
            for (int kt = 0; kt < 4; ++kt) {
                o[kt] = __builtin_amdgcn_mfma_f32_16x16x32_bf16(pa0, vb0[kt], o[kt], 0, 0, 0);
                o[kt] = __builtin_amdgcn_mfma_f32_16x16x32_bf16(pa1, vb1[kt], o[kt], 0, 0, 0);
            }
        }
    }
    // partial epilogue: no division; o -> bf16, l -> f32
    #pragma unroll
    for (int i = 0; i < 4; ++i) {
        float t = lrp[i];
        t += __shfl_xor(t, 1, 64); t += __shfl_xor(t, 2, 64);
        t += __shfl_xor(t, 4, 64); t += __shfl_xor(t, 8, 64);
        const int row = n0 + wave * 16 + kg * 4 + i;
        if (lrow == 0) lpart[(size_t)(sp * NH + h) * NTOK + row] = t;
        #pragma unroll
        for (int kt = 0; kt < 4; ++kt)
            opart[((size_t)(sp * NH + h) * NTOK + row) * DH + kt * 16 + lrow]
                = f2bf(o[kt][i]);
    }
}

// ---------- attn_combine: A1bf[n][h*DH+c] = sum_s opart / sum_s lpart ----------
__global__ __launch_bounds__(256) void attn_combine_kernel(
    const unsigned short* __restrict__ opart, const float* __restrict__ lpart,
    unsigned short* __restrict__ A1bf)
{
    const int flat = blockIdx.x * 256 + threadIdx.x;   // 0..262143
    const int n = flat >> 7;
    const int u = flat & 127;
    const int h = u >> 3, c0 = (u & 7) * 8;
    float sum[8] = {0.f, 0.f, 0.f, 0.f, 0.f, 0.f, 0.f, 0.f};
    float l = 0.f;
    #pragma unroll
    for (int s = 0; s < SPLIT; ++s) {
        const unsigned short* p = opart + ((size_t)(s * NH + h) * NTOK + n) * DH + c0;
        ushort4 a = *(const ushort4*)p;
        ushort4 b = *(const ushort4*)(p + 4);
        sum[0] += bf2f(a.x); sum[1] += bf2f(a.y); sum[2] += bf2f(a.z); sum[3] += bf2f(a.w);
        sum[4] += bf2f(b.x); sum[5] += bf2f(b.y); sum[6] += bf2f(b.z); sum[7] += bf2f(b.w);
        l += lpart[(size_t)(s * NH + h) * NTOK + n];
    }
    const float inv = 1.f / l;
    ushort4 u0, u1;
    u0.x = f2bf(sum[0] * inv); u0.y = f2bf(sum[1] * inv);
    u0.z = f2bf(sum[2] * inv); u0.w = f2bf(sum[3] * inv);
    u1.x = f2bf(sum[4] * inv); u1.y = f2bf(sum[5] * inv);
    u1.z = f2bf(sum[6] * inv); u1.w = f2bf(sum[7] * inv);
    unsigned short* dst = A1bf + (size_t)n * (NH * DH) + h * DH + c0;
    *(ushort4*)dst       = u0;
    *(ushort4*)(dst + 4) = u1;
}

// ---------- outlin (MFMA): out[n,j] = sum_c A1[n,c]*W0[j,c] + b0[j] ----------
__global__ __launch_bounds__(256) void outlin_mfma_kernel(
    const unsigned short* __restrict__ A1bf, const unsigned short* __restrict__ W0bf,
    const float* __restrict__ b0, float* __restrict__ outA)
{
    const int j0 = blockIdx.x * 64, n0 = blockIdx.y * 64;
    const int wave = threadIdx.x >> 6, lane = threadIdx.x & 63;
    const int lrow = lane & 15, kg = lane >> 4;
    const unsigned short* ar = A1bf + (size_t)(n0 + wave * 16 + lrow) * (NH * DH);

    f32x4 acc[4];
    #pragma unroll
    for (int jt = 0; jt < 4; ++jt) acc[jt] = (f32x4){0.f, 0.f, 0.f, 0.f};

    for (int c0 = 0; c0 < NH * DH; c0 += 32) {
        bf16x8 a = *(const bf16x8*)(ar + c0 + kg * 8);
        #pragma unroll
        for (int jt = 0; jt < 4; ++jt) {
            bf16x8 b = *(const bf16x8*)(W0bf + (size_t)(j0 + jt * 16 + lrow) * (NH * DH) + c0 + kg * 8);
            acc[jt] = __builtin_amdgcn_mfma_f32_16x16x32_bf16(a, b, acc[jt], 0, 0, 0);
        }
    }
    #pragma unroll
    for (int jt = 0; jt < 4; ++jt) {
        const float bb = b0[j0 + jt * 16 + lrow];
        #pragma unroll
        for (int i = 0; i < 4; ++i)
            outA[(size_t)(n0 + wave * 16 + kg * 4 + i) * (NH * DH) + j0 + jt * 16 + lrow]
                = acc[jt][i] + bb;
    }
}

extern "C" void kernel_launch(void* const* d_in, const int* in_sizes, int n_in,
                              void* d_out, int out_size, void* d_ws, size_t ws_size,
                              hipStream_t stream)
{
    const float* Q  = (const float*)d_in[0];
    const float* K  = (const float*)d_in[1];
    const float* V  = (const float*)d_in[2];
    const float* Wq = (const float*)d_in[3];
    const float* Wk = (const float*)d_in[4];
    const float* Wv = (const float*)d_in[5];
    const float* W0 = (const float*)d_in[6];
    const float* b0 = (const float*)d_in[7];

    float* logits = (float*)d_out;                                 // [H][N][N]
    float* outA   = (float*)d_out + (size_t)NH * NTOK * NTOK;      // [N][H*DH]

    // ws layout (~42.5 MB):
    //   fixed: Wt | W0bf | Qbf | Knbf | Vt | A1bf
    //   union: Xbf (dead after proj)  OVERLAYS  opart+lpart (written by attn)
    char* p = (char*)d_ws;
    unsigned short* Wt   = (unsigned short*)p;  p += (size_t)3 * NH * DH * DM * 2;   // 6.29 MB
    unsigned short* W0bf = (unsigned short*)p;  p += (size_t)DM * DM * 2;            // 2.10 MB
    unsigned short* Qbf  = (unsigned short*)p;  p += (size_t)NH * NTOK * DH * 2;     // 4.19 MB
    unsigned short* Knbf = (unsigned short*)p;  p += (size_t)NH * NTOK * DH * 2;
    unsigned short* Vt   = (unsigned short*)p;  p += (size_t)NH * NTOK * DH * 2;
    unsigned short* A1bf = (unsigned short*)p;  p += (size_t)NH * NTOK * DH * 2;
    unsigned short* Xbf  = (unsigned short*)p;                       // 12.58 MB (dead after proj)
    unsigned short* opart = (unsigned short*)p;                      // 16.78 MB (overlays Xbf)
    float* lpart = (float*)(p + (size_t)SPLIT * NH * NTOK * DH * 2); // 0.52 MB

    castX_kernel     <<<dim3(NTOK * DM / (256 * 8), 3), 256, 0, stream>>>(Q, K, V, Xbf);
    castWt_kernel    <<<dim3(DM / 64, NH, 3), 256, 0, stream>>>(Wq, Wk, Wv, Wt);
    castW0_kernel    <<<dim3(DM * DM / 1024), 256, 0, stream>>>(W0, W0bf);
    proj_mfma_kernel <<<dim3(NTOK / 64, NH, 3), 256, 0, stream>>>(Xbf, Wt, Qbf, Knbf, Vt);
    fused_attn_kernel<<<dim3(NH, NTOK / 64, SPLIT), 256, 0, stream>>>(Qbf, Knbf, Vt, logits, opart, lpart);
    attn_combine_kernel<<<dim3(NTOK * NH * DH / (256 * 8)), 256, 0, stream>>>(opart, lpart, A1bf);
    outlin_mfma_kernel<<<dim3(NH * DH / 64, NTOK / 64), 256, 0, stream>>>(A1bf, W0bf, b0, outA);
}